// Round 3
// baseline (89.206 us; speedup 1.0000x reference)
//
#include <hip/hip_runtime.h>
#include <stdint.h>

typedef __bf16 bf16x8 __attribute__((ext_vector_type(8)));
typedef float  f32x4  __attribute__((ext_vector_type(4)));

typedef __attribute__((address_space(1))) const void g_void;
typedef __attribute__((address_space(3))) void l_void;

constexpr int NB = 32, TT = 2048, JJ = 512, DD = 256;
constexpr int BM = 128, BN = 128, BK = 32;
constexpr int KSTEPS = DD / BK;   // 8

// LDS map (bytes):
//   buf0: A [0,16384) B [16384,32768)   f32[128][32], 16-B chunks, chunk' = c ^ (row&7)
//   buf1: A [32768,49152) B [49152,65536)
//   w_s [65536,68608)  768 f32 (wc|wq|wm)
//   c_s [68608,69120)  q_s [69120,69632)
// 69632 B -> 2 blocks/CU by LDS.

__global__ __launch_bounds__(256, 2)
void sim_kernel(const float* __restrict__ ctx, const float* __restrict__ que,
                const float* __restrict__ wvec, float* __restrict__ out)
{
    __shared__ __align__(1024) unsigned char lds[69632];
    float* w_s = (float*)(lds + 65536);
    float* c_s = (float*)(lds + 68608);
    float* q_s = (float*)(lds + 69120);

    const int tid = threadIdx.x;
    const int l   = tid & 63;
    const int wid = tid >> 6;

    // XCD-aware swizzle: each XCD gets 256 consecutive work-ids.
    const int pb = blockIdx.x;
    const int id = (pb & 7) * 256 + (pb >> 3);
    const int n0 = (id & 3) * BN;
    const int m0 = ((id >> 2) & 15) * BM;
    const int bI = id >> 6;

    // ---- prologue: weights + term accumulators into LDS (drained before 1st barrier)
    if (tid < 192) *(f32x4*)(w_s + tid * 4) = *(const f32x4*)(wvec + tid * 4);
    if (tid < 128) { c_s[tid] = 0.f; q_s[tid] = 0.f; }
    asm volatile("s_waitcnt lgkmcnt(0)" ::: "memory");

    // ---- DMA staging geometry: waves 0,1 -> A rows 0-63/64-127; waves 2,3 -> B.
    const int rsub = l >> 3, csub = l & 7;
    const int regionRow0 = (wid & 1) * 64;
    const bool isA = (wid < 2);
    const float* srcBase = isA
        ? (ctx + ((size_t)bI * TT + m0 + regionRow0) * DD)
        : (que + ((size_t)bI * JJ + n0 + regionRow0) * DD);
    const float* lane_src = srcBase + (size_t)rsub * DD + ((csub ^ rsub) << 2); // pre-swizzled src
    unsigned char* ldsRegion = lds + (isA ? 0 : 16384) + regionRow0 * 128;

    auto stage = [&](int ks, int buf) {
        const float* s = lane_src + ks * BK;
        unsigned char* dst = ldsRegion + buf * 32768;
        #pragma unroll
        for (int i = 0; i < 8; ++i)
            __builtin_amdgcn_global_load_lds((g_void*)(s + (size_t)i * 8 * DD),
                                             (l_void*)(dst + i * 1024), 16, 0, 0);
    };

    stage(0, 0);           // 8 loads
    stage(1, 1);           // 16 outstanding

    f32x4 acc[4][4];
    #pragma unroll
    for (int m = 0; m < 4; ++m)
        #pragma unroll
        for (int n = 0; n < 4; ++n) acc[m][n] = f32x4{0.f, 0.f, 0.f, 0.f};

    const int wm_0 = (wid >> 1) * 64;
    const int wn_0 = (wid & 1) * 64;
    const int lr  = l & 15;
    const int hi  = l >> 4;
    const int c0  = hi * 2;
    const int ksl = hi * 8;
    const bool doC = ((wid & 1) == 0);  // waves 0,2 own c_term rows
    const bool doQ = (wid < 2);         // waves 0,1 own q_term cols

    #pragma unroll
    for (int k = 0; k < KSTEPS; ++k) {
        // counted vmcnt: stage(k) drained, stage(k+1) stays in flight across barrier
        if (k == KSTEPS - 1) asm volatile("s_waitcnt vmcnt(0)" ::: "memory");
        else                 asm volatile("s_waitcnt vmcnt(8)" ::: "memory");
        __builtin_amdgcn_s_barrier();

        const unsigned char* bufA = lds + (k & 1) * 32768;
        const unsigned char* bufB = bufA + 16384;

        f32x4 wmA = *(f32x4*)(w_s + 512 + k * BK + ksl);
        f32x4 wmB = *(f32x4*)(w_s + 512 + k * BK + ksl + 4);
        f32x4 wcA, wcB, wqA, wqB;
        if (doC) { wcA = *(f32x4*)(w_s + k * BK + ksl);       wcB = *(f32x4*)(w_s + k * BK + ksl + 4); }
        if (doQ) { wqA = *(f32x4*)(w_s + 256 + k * BK + ksl); wqB = *(f32x4*)(w_s + 256 + k * BK + ksl + 4); }

        bf16x8 af[4], bfr[4];

        #pragma unroll
        for (int n = 0; n < 4; ++n) {
            const int r  = wn_0 + n * 16 + lr;
            const int sw = r & 7;
            const unsigned char* rp = bufB + r * 128;
            f32x4 x0 = *(const f32x4*)(rp + ((c0 ^ sw) << 4));
            f32x4 x1 = *(const f32x4*)(rp + (((c0 + 1) ^ sw) << 4));
            bf16x8 pk;
            #pragma unroll
            for (int i = 0; i < 4; ++i) { pk[i] = (__bf16)x0[i]; pk[4 + i] = (__bf16)x1[i]; }
            bfr[n] = pk;
            if (doQ) {
                float qp = x0[0]*wqA[0] + x0[1]*wqA[1] + x0[2]*wqA[2] + x0[3]*wqA[3]
                         + x1[0]*wqB[0] + x1[1]*wqB[1] + x1[2]*wqB[2] + x1[3]*wqB[3];
                qp += __shfl_xor(qp, 16);
                qp += __shfl_xor(qp, 32);
                if (l < 16) q_s[wn_0 + n * 16 + l] += qp;
            }
        }

        #pragma unroll
        for (int m = 0; m < 4; ++m) {
            const int r  = wm_0 + m * 16 + lr;
            const int sw = r & 7;
            const unsigned char* rp = bufA + r * 128;
            f32x4 x0 = *(const f32x4*)(rp + ((c0 ^ sw) << 4));
            f32x4 x1 = *(const f32x4*)(rp + (((c0 + 1) ^ sw) << 4));
            bf16x8 pk;
            #pragma unroll
            for (int i = 0; i < 4; ++i) {
                pk[i]     = (__bf16)(x0[i] * wmA[i]);
                pk[4 + i] = (__bf16)(x1[i] * wmB[i]);
            }
            af[m] = pk;
            if (doC) {
                float cp = x0[0]*wcA[0] + x0[1]*wcA[1] + x0[2]*wcA[2] + x0[3]*wcA[3]
                         + x1[0]*wcB[0] + x1[1]*wcB[1] + x1[2]*wcB[2] + x1[3]*wcB[3];
                cp += __shfl_xor(cp, 16);
                cp += __shfl_xor(cp, 32);
                if (l < 16) c_s[wm_0 + m * 16 + l] += cp;
            }
        }

        __builtin_amdgcn_s_barrier();      // all waves done reading buf[k&1]
        if (k + 2 < KSTEPS) stage(k + 2, k & 1);   // overwrite it, 2 tiles ahead

        __builtin_amdgcn_s_setprio(1);
        #pragma unroll
        for (int m = 0; m < 4; ++m)
            #pragma unroll
            for (int n = 0; n < 4; ++n)
                acc[m][n] = __builtin_amdgcn_mfma_f32_16x16x32_bf16(af[m], bfr[n], acc[m][n], 0, 0, 0);
        __builtin_amdgcn_s_setprio(0);
    }

    __syncthreads();   // c_s/q_s complete (drains lgkm; no DMA outstanding here)

    // ---- epilogue: D lane mapping col=l&15, row=hi*4+q
    const int lq = hi * 4;
    #pragma unroll
    for (int m = 0; m < 4; ++m) {
        const int rowL = wm_0 + m * 16 + lq;
        const f32x4 cv = *(f32x4*)(c_s + rowL);
        #pragma unroll
        for (int n = 0; n < 4; ++n) {
            const int colL = wn_0 + n * 16 + lr;
            const float qv = q_s[colL];
            float* dst = out + ((size_t)bI * TT + m0 + rowL) * JJ + (n0 + colL);
            const f32x4 v = acc[m][n];
            #pragma unroll
            for (int q = 0; q < 4; ++q)
                dst[(size_t)q * JJ] = v[q] + cv[q] + qv;
        }
    }
}

extern "C" void kernel_launch(void* const* d_in, const int* in_sizes, int n_in,
                              void* d_out, int out_size, void* d_ws, size_t ws_size,
                              hipStream_t stream) {
    (void)in_sizes; (void)n_in; (void)d_ws; (void)ws_size; (void)out_size;
    const float* ctx = (const float*)d_in[0];
    const float* que = (const float*)d_in[1];
    const float* wv  = (const float*)d_in[2];
    float* out = (float*)d_out;

    sim_kernel<<<dim3(2048), dim3(256), 0, stream>>>(ctx, que, wv, out);
}